// Round 1
// baseline (2402.110 us; speedup 1.0000x reference)
//
#include <hip/hip_runtime.h>
#include <math.h>

#define IN_DIMC 300
#define MEMC    300
#define BBC     32
#define DDC     11
#define NNC     ((1 << DDC) - 1)   // 2047

__device__ __forceinline__ float fsig(float x)  { return 1.0f / (1.0f + __expf(-x)); }
__device__ __forceinline__ float ftanh_(float x){ return 2.0f / (1.0f + __expf(-2.0f * x)) - 1.0f; }

// ---------------------------------------------------------------------------
// Leaf level (l = D-1): i = sig(x@Wix + bix + bih), o = sig(x@Wox + box + boh),
// u = tanh(x@Wux + bux + buh); c = i*u; h = o*tanh(c)
// ---------------------------------------------------------------------------
template <int TM>
__global__ __launch_bounds__(320)
void leaf_k(const float* __restrict__ embs,
            const float* __restrict__ Wix, const float* __restrict__ Wox,
            const float* __restrict__ Wux,
            const float* __restrict__ bix, const float* __restrict__ bih,
            const float* __restrict__ box, const float* __restrict__ boh,
            const float* __restrict__ bux, const float* __restrict__ buh,
            float* __restrict__ h, float* __restrict__ c)
{
    const int L    = 1 << (DDC - 1);   // 1024
    const int base = L - 1;            // 1023
    __shared__ float xs[IN_DIMC][TM];

    const int row0 = blockIdx.x * TM;

    for (int t = threadIdx.x; t < TM * IN_DIMC; t += blockDim.x) {
        int r = t / IN_DIMC, k = t - r * IN_DIMC;
        int row = row0 + r;
        int b = row >> (DDC - 1);
        int off = row & (L - 1);
        xs[k][r] = embs[((size_t)b * NNC + base + off) * IN_DIMC + k];
    }
    __syncthreads();

    const int j = threadIdx.x;
    if (j >= MEMC) return;

    float ai[TM], ao[TM], au[TM];
#pragma unroll
    for (int r = 0; r < TM; ++r) { ai[r] = 0.f; ao[r] = 0.f; au[r] = 0.f; }

    for (int k = 0; k < IN_DIMC; ++k) {
        float vwi = Wix[k * MEMC + j];
        float vwo = Wox[k * MEMC + j];
        float vwu = Wux[k * MEMC + j];
#pragma unroll
        for (int r = 0; r < TM; ++r) {
            float x = xs[k][r];
            ai[r] = fmaf(x, vwi, ai[r]);
            ao[r] = fmaf(x, vwo, ao[r]);
            au[r] = fmaf(x, vwu, au[r]);
        }
    }

    const float bi = bix[j] + bih[j];
    const float bo = box[j] + boh[j];
    const float bu = bux[j] + buh[j];

#pragma unroll
    for (int r = 0; r < TM; ++r) {
        int row = row0 + r;
        int b = row >> (DDC - 1);
        int off = row & (L - 1);
        size_t o = ((size_t)b * NNC + base + off) * MEMC + j;
        float ig = fsig(ai[r] + bi);
        float og = fsig(ao[r] + bo);
        float ug = ftanh_(au[r] + bu);
        float cv = ig * ug;
        c[o] = cv;
        h[o] = og * ftanh_(cv);
    }
}

// ---------------------------------------------------------------------------
// Internal level l: per node n with children 2n+1, 2n+2:
//   hs = h1 + h2
//   i = sig(x@Wix + hs@Wih + bix + bih)
//   o = sig(x@Wox + hs@Woh + box + boh)
//   u = tanh(x@Wux + hs@Wuh + bux + buh)
//   f1 = sig(x@Wfx + h1@Wfh + bfx + bfh)
//   f2 = sig(x@Wfx + h2@Wfh + bfx + bfh)
//   c = i*u + f1*c1 + f2*c2 ; h = o*tanh(c)
// ---------------------------------------------------------------------------
template <int TM>
__global__ __launch_bounds__(320)
void node_k(const float* __restrict__ embs,
            const float* __restrict__ Wix, const float* __restrict__ Wih,
            const float* __restrict__ Wfx, const float* __restrict__ Wfh,
            const float* __restrict__ Wox, const float* __restrict__ Woh,
            const float* __restrict__ Wux, const float* __restrict__ Wuh,
            const float* __restrict__ bix, const float* __restrict__ bih,
            const float* __restrict__ bfx, const float* __restrict__ bfh,
            const float* __restrict__ box, const float* __restrict__ boh,
            const float* __restrict__ bux, const float* __restrict__ buh,
            float* __restrict__ h, float* __restrict__ c, int lvl)
{
    const int L    = 1 << lvl;
    const int base = L - 1;
    __shared__ float xs [IN_DIMC][TM];
    __shared__ float hss[MEMC][TM];
    __shared__ float h1s[MEMC][TM];

    const int row0 = blockIdx.x * TM;

    for (int t = threadIdx.x; t < TM * IN_DIMC; t += blockDim.x) {
        int r = t / IN_DIMC, k = t - r * IN_DIMC;
        int row = row0 + r;
        int b = row >> lvl;
        int off = row & (L - 1);
        int node = base + off;
        xs[k][r] = embs[((size_t)b * NNC + node) * IN_DIMC + k];
        float h1 = h[((size_t)b * NNC + 2 * node + 1) * MEMC + k];
        float h2 = h[((size_t)b * NNC + 2 * node + 2) * MEMC + k];
        h1s[k][r] = h1;
        hss[k][r] = h1 + h2;
    }
    __syncthreads();

    const int j = threadIdx.x;
    if (j >= MEMC) return;

    float ai[TM], ao[TM], au[TM], afx[TM], af1[TM], af2[TM];
#pragma unroll
    for (int r = 0; r < TM; ++r) {
        ai[r] = 0.f; ao[r] = 0.f; au[r] = 0.f;
        afx[r] = 0.f; af1[r] = 0.f; af2[r] = 0.f;
    }

    for (int k = 0; k < IN_DIMC; ++k) {
        float vix = Wix[k * MEMC + j];
        float vih = Wih[k * MEMC + j];
        float vfx = Wfx[k * MEMC + j];
        float vfh = Wfh[k * MEMC + j];
        float vox = Wox[k * MEMC + j];
        float voh = Woh[k * MEMC + j];
        float vux = Wux[k * MEMC + j];
        float vuh = Wuh[k * MEMC + j];
#pragma unroll
        for (int r = 0; r < TM; ++r) {
            float x  = xs[k][r];
            float hs = hss[k][r];
            float h1 = h1s[k][r];
            float h2 = hs - h1;
            ai[r]  = fmaf(x,  vix, ai[r]);
            ai[r]  = fmaf(hs, vih, ai[r]);
            ao[r]  = fmaf(x,  vox, ao[r]);
            ao[r]  = fmaf(hs, voh, ao[r]);
            au[r]  = fmaf(x,  vux, au[r]);
            au[r]  = fmaf(hs, vuh, au[r]);
            afx[r] = fmaf(x,  vfx, afx[r]);
            af1[r] = fmaf(h1, vfh, af1[r]);
            af2[r] = fmaf(h2, vfh, af2[r]);
        }
    }

    const float bi = bix[j] + bih[j];
    const float bo = box[j] + boh[j];
    const float bu = bux[j] + buh[j];
    const float bf = bfx[j] + bfh[j];

#pragma unroll
    for (int r = 0; r < TM; ++r) {
        int row = row0 + r;
        int b = row >> lvl;
        int off = row & (L - 1);
        int node = base + off;
        size_t o  = ((size_t)b * NNC + node) * MEMC + j;
        size_t o1 = ((size_t)b * NNC + 2 * node + 1) * MEMC + j;
        size_t o2 = ((size_t)b * NNC + 2 * node + 2) * MEMC + j;
        float ig = fsig(ai[r] + bi);
        float og = fsig(ao[r] + bo);
        float ug = ftanh_(au[r] + bu);
        float f1 = fsig(afx[r] + af1[r] + bf);
        float f2 = fsig(afx[r] + af2[r] + bf);
        float cn = ig * ug + f1 * c[o1] + f2 * c[o2];
        c[o] = cn;
        h[o] = og * ftanh_(cn);
    }
}

// ---------------------------------------------------------------------------
extern "C" void kernel_launch(void* const* d_in, const int* in_sizes, int n_in,
                              void* d_out, int out_size, void* d_ws, size_t ws_size,
                              hipStream_t stream)
{
    const float* embs = (const float*)d_in[0];
    const float* Wix  = (const float*)d_in[1];
    const float* bix  = (const float*)d_in[2];
    const float* Wih  = (const float*)d_in[3];
    const float* bih  = (const float*)d_in[4];
    const float* Wfx  = (const float*)d_in[5];
    const float* bfx  = (const float*)d_in[6];
    const float* Wfh  = (const float*)d_in[7];
    const float* bfh  = (const float*)d_in[8];
    const float* Wox  = (const float*)d_in[9];
    const float* box_ = (const float*)d_in[10];
    const float* Woh  = (const float*)d_in[11];
    const float* boh  = (const float*)d_in[12];
    const float* Wux  = (const float*)d_in[13];
    const float* bux  = (const float*)d_in[14];
    const float* Wuh  = (const float*)d_in[15];
    const float* buh  = (const float*)d_in[16];

    float* h = (float*)d_out;           // (B, N, MEM) fp32
    float* c = (float*)d_ws;            // (B, N, MEM) fp32 scratch

    constexpr int TM = 8;

    // Leaf level
    {
        int rows = BBC << (DDC - 1);    // 32768
        leaf_k<TM><<<rows / TM, 320, 0, stream>>>(
            embs, Wix, Wox, Wux, bix, bih, box_, boh, bux, buh, h, c);
    }

    // Internal levels, bottom-up
    for (int lvl = DDC - 2; lvl >= 0; --lvl) {
        int rows = BBC << lvl;
        node_k<TM><<<rows / TM, 320, 0, stream>>>(
            embs, Wix, Wih, Wfx, Wfh, Wox, Woh, Wux, Wuh,
            bix, bih, bfx, bfh, box_, boh, bux, buh, h, c, lvl);
    }
}

// Round 2
// 920.005 us; speedup vs baseline: 2.6110x; 2.6110x over previous
//
#include <hip/hip_runtime.h>
#include <math.h>

#define IN_DIMC 300
#define MEMC    300
#define BBC     32
#define DDC     11
#define NNC     2047
#define KT_N    10          // K-tiles of 32 per phase (K padded 300->320)
#define NT_N    20          // N-tiles of 16      (N padded 300->320)
#define KP      328         // LDS row stride in bf16 elems (656B: 16B-aligned, bank-friendly)

typedef __attribute__((ext_vector_type(8))) short bf16x8;   // 8 bf16 = 4 VGPRs
typedef __attribute__((ext_vector_type(4))) float f32x4;    // MFMA accumulator

// Pre-packed bf16 weight fragments: [w][kt][nt][lane][8], frag = 1KB, total 1.6MB
__device__ __align__(16) unsigned short g_Wp[8][KT_N][NT_N][64][8];

__device__ __forceinline__ float fsig(float x)  { return 1.0f / (1.0f + __expf(-x)); }
__device__ __forceinline__ float ftanh_(float x){ return 2.0f / (1.0f + __expf(-2.0f * x)) - 1.0f; }
__device__ __forceinline__ unsigned short f2bf(float f) {   // RNE fp32 -> bf16
    unsigned int u = __float_as_uint(f);
    u += 0x7FFFu + ((u >> 16) & 1u);
    return (unsigned short)(u >> 16);
}

// ---------------------------------------------------------------------------
// Pack 8 weight matrices (fp32, [K=300][N=300]) into bf16 B-fragment layout.
// WID: 0=ix 1=ih 2=fx 3=fh 4=ox 5=oh 6=ux 7=uh
// ---------------------------------------------------------------------------
__global__ void pack_w(const float* __restrict__ Wix, const float* __restrict__ Wih,
                       const float* __restrict__ Wfx, const float* __restrict__ Wfh,
                       const float* __restrict__ Wox, const float* __restrict__ Woh,
                       const float* __restrict__ Wux, const float* __restrict__ Wuh)
{
    int gid = blockIdx.x * blockDim.x + threadIdx.x;
    const int total = 8 * KT_N * NT_N * 64;
    if (gid >= total) return;
    int l  = gid & 63;
    int f  = gid >> 6;                 // fragment id
    int nt = f % NT_N;
    int kt = (f / NT_N) % KT_N;
    int w  = f / (NT_N * KT_N);
    const float* Ws[8] = {Wix, Wih, Wfx, Wfh, Wox, Woh, Wux, Wuh};
    const float* src = Ws[w];
    int n  = nt * 16 + (l & 15);
    int k0 = kt * 32 + 8 * (l >> 4);
    unsigned short tmp[8];
#pragma unroll
    for (int i = 0; i < 8; ++i) {
        int k = k0 + i;
        float v = (n < MEMC && k < IN_DIMC) ? src[k * MEMC + n] : 0.0f;
        tmp[i] = f2bf(v);
    }
    *reinterpret_cast<uint4*>(&g_Wp[w][kt][nt][l][0]) = *reinterpret_cast<const uint4*>(tmp);
}

// ---------------------------------------------------------------------------
// Leaf level: i,o,u from x only. c = i*u; h = o*tanh(c)
// Block: 16 rows x 300 cols, 5 waves, wave w owns N-tiles 4w..4w+3
// ---------------------------------------------------------------------------
__global__ __launch_bounds__(320)
void leaf_k(const float* __restrict__ embs,
            const float* __restrict__ bix, const float* __restrict__ bih,
            const float* __restrict__ box_, const float* __restrict__ boh,
            const float* __restrict__ bux, const float* __restrict__ buh,
            float* __restrict__ h, float* __restrict__ c)
{
    const int L = 1 << (DDC - 1);      // 1024
    const int base = L - 1;
    __shared__ __align__(16) unsigned short xs[16][KP];

    const int tid = threadIdx.x;
    // zero LDS (covers K-pad)
    {
        unsigned long long* z = reinterpret_cast<unsigned long long*>(&xs[0][0]);
        for (int t = tid; t < 16 * KP / 4; t += 320) z[t] = 0ull;
    }
    __syncthreads();

    const int row0 = blockIdx.x * 16;
    for (int t = tid; t < 16 * IN_DIMC; t += 320) {
        int r = t / IN_DIMC, k = t - r * IN_DIMC;
        int row = row0 + r;
        int b = row >> (DDC - 1);
        int off = row & (L - 1);
        float v = embs[((size_t)b * NNC + base + off) * IN_DIMC + k];
        xs[r][k] = f2bf(v);
    }
    __syncthreads();

    const int lane = tid & 63;
    const int nt0 = (tid >> 6) * 4;

    f32x4 aI[4], aO[4], aU[4];
    const f32x4 zv = {0.f, 0.f, 0.f, 0.f};
#pragma unroll
    for (int t = 0; t < 4; ++t) { aI[t] = zv; aO[t] = zv; aU[t] = zv; }

#pragma unroll
    for (int kt = 0; kt < KT_N; ++kt) {
        bf16x8 ax = *reinterpret_cast<const bf16x8*>(&xs[lane & 15][kt * 32 + 8 * (lane >> 4)]);
#pragma unroll
        for (int t = 0; t < 4; ++t) {
            int nt = nt0 + t;
            bf16x8 wI = *reinterpret_cast<const bf16x8*>(&g_Wp[0][kt][nt][lane][0]);
            bf16x8 wO = *reinterpret_cast<const bf16x8*>(&g_Wp[4][kt][nt][lane][0]);
            bf16x8 wU = *reinterpret_cast<const bf16x8*>(&g_Wp[6][kt][nt][lane][0]);
            aI[t] = __builtin_amdgcn_mfma_f32_16x16x32_bf16(ax, wI, aI[t], 0, 0, 0);
            aO[t] = __builtin_amdgcn_mfma_f32_16x16x32_bf16(ax, wO, aO[t], 0, 0, 0);
            aU[t] = __builtin_amdgcn_mfma_f32_16x16x32_bf16(ax, wU, aU[t], 0, 0, 0);
        }
    }

#pragma unroll
    for (int t = 0; t < 4; ++t) {
        int col = (nt0 + t) * 16 + (lane & 15);
        if (col < MEMC) {
            float bI = bix[col] + bih[col];
            float bO = box_[col] + boh[col];
            float bU = bux[col] + buh[col];
#pragma unroll
            for (int r = 0; r < 4; ++r) {
                int row = row0 + 4 * (lane >> 4) + r;
                int b = row >> (DDC - 1);
                int off = row & (L - 1);
                size_t o = ((size_t)b * NNC + base + off) * (size_t)MEMC + col;
                float ig = fsig(aI[t][r] + bI);
                float og = fsig(aO[t][r] + bO);
                float ug = ftanh_(aU[t][r] + bU);
                float cv = ig * ug;
                c[o] = cv;
                h[o] = og * ftanh_(cv);
            }
        }
    }
}

// ---------------------------------------------------------------------------
// Internal level: 9 accumulation streams via 6 accumulators:
//   x-phase: aI+=x@Wix aO+=x@Wox aU+=x@Wux aFX=x@Wfx
//   h-phase: aI+=hs@Wih aO+=hs@Woh aU+=hs@Wuh aFS=hs@Wfh aF1=h1@Wfh
//   f1 = sig(aFX+aF1+bf); f2 = sig(aFX+(aFS-aF1)+bf)
// ---------------------------------------------------------------------------
__global__ __launch_bounds__(320)
void node_k(const float* __restrict__ embs,
            const float* __restrict__ bix, const float* __restrict__ bih,
            const float* __restrict__ bfx, const float* __restrict__ bfh,
            const float* __restrict__ box_, const float* __restrict__ boh,
            const float* __restrict__ bux, const float* __restrict__ buh,
            float* __restrict__ h, float* __restrict__ c, int lvl)
{
    const int L = 1 << lvl;
    const int base = L - 1;
    __shared__ __align__(16) unsigned short xs [16][KP];
    __shared__ __align__(16) unsigned short hss[16][KP];
    __shared__ __align__(16) unsigned short h1s[16][KP];

    const int tid = threadIdx.x;
    {
        unsigned long long* z = reinterpret_cast<unsigned long long*>(&xs[0][0]);
        for (int t = tid; t < 16 * KP / 4; t += 320) z[t] = 0ull;
        unsigned long long* z2 = reinterpret_cast<unsigned long long*>(&hss[0][0]);
        for (int t = tid; t < 16 * KP / 4; t += 320) z2[t] = 0ull;
        unsigned long long* z3 = reinterpret_cast<unsigned long long*>(&h1s[0][0]);
        for (int t = tid; t < 16 * KP / 4; t += 320) z3[t] = 0ull;
    }
    __syncthreads();

    const int row0 = blockIdx.x * 16;
    for (int t = tid; t < 16 * IN_DIMC; t += 320) {
        int r = t / IN_DIMC, k = t - r * IN_DIMC;
        int row = row0 + r;
        int b = row >> lvl;
        int off = row & (L - 1);
        int node = base + off;
        float v = embs[((size_t)b * NNC + node) * IN_DIMC + k];
        xs[r][k] = f2bf(v);
        float h1v = h[((size_t)b * NNC + 2 * node + 1) * MEMC + k];
        float h2v = h[((size_t)b * NNC + 2 * node + 2) * MEMC + k];
        h1s[r][k] = f2bf(h1v);
        hss[r][k] = f2bf(h1v + h2v);
    }
    __syncthreads();

    const int lane = tid & 63;
    const int nt0 = (tid >> 6) * 4;

    f32x4 aI[4], aO[4], aU[4], aFX[4], aFS[4], aF1[4];
    const f32x4 zv = {0.f, 0.f, 0.f, 0.f};
#pragma unroll
    for (int t = 0; t < 4; ++t) {
        aI[t] = zv; aO[t] = zv; aU[t] = zv; aFX[t] = zv; aFS[t] = zv; aF1[t] = zv;
    }

    // x-phase
#pragma unroll
    for (int kt = 0; kt < KT_N; ++kt) {
        bf16x8 ax = *reinterpret_cast<const bf16x8*>(&xs[lane & 15][kt * 32 + 8 * (lane >> 4)]);
#pragma unroll
        for (int t = 0; t < 4; ++t) {
            int nt = nt0 + t;
            bf16x8 wI = *reinterpret_cast<const bf16x8*>(&g_Wp[0][kt][nt][lane][0]);
            bf16x8 wF = *reinterpret_cast<const bf16x8*>(&g_Wp[2][kt][nt][lane][0]);
            bf16x8 wO = *reinterpret_cast<const bf16x8*>(&g_Wp[4][kt][nt][lane][0]);
            bf16x8 wU = *reinterpret_cast<const bf16x8*>(&g_Wp[6][kt][nt][lane][0]);
            aI[t]  = __builtin_amdgcn_mfma_f32_16x16x32_bf16(ax, wI, aI[t],  0, 0, 0);
            aFX[t] = __builtin_amdgcn_mfma_f32_16x16x32_bf16(ax, wF, aFX[t], 0, 0, 0);
            aO[t]  = __builtin_amdgcn_mfma_f32_16x16x32_bf16(ax, wO, aO[t],  0, 0, 0);
            aU[t]  = __builtin_amdgcn_mfma_f32_16x16x32_bf16(ax, wU, aU[t],  0, 0, 0);
        }
    }
    // h-phase
#pragma unroll
    for (int kt = 0; kt < KT_N; ++kt) {
        bf16x8 ahs = *reinterpret_cast<const bf16x8*>(&hss[lane & 15][kt * 32 + 8 * (lane >> 4)]);
        bf16x8 ah1 = *reinterpret_cast<const bf16x8*>(&h1s[lane & 15][kt * 32 + 8 * (lane >> 4)]);
#pragma unroll
        for (int t = 0; t < 4; ++t) {
            int nt = nt0 + t;
            bf16x8 wI = *reinterpret_cast<const bf16x8*>(&g_Wp[1][kt][nt][lane][0]);
            bf16x8 wF = *reinterpret_cast<const bf16x8*>(&g_Wp[3][kt][nt][lane][0]);
            bf16x8 wO = *reinterpret_cast<const bf16x8*>(&g_Wp[5][kt][nt][lane][0]);
            bf16x8 wU = *reinterpret_cast<const bf16x8*>(&g_Wp[7][kt][nt][lane][0]);
            aI[t]  = __builtin_amdgcn_mfma_f32_16x16x32_bf16(ahs, wI, aI[t],  0, 0, 0);
            aO[t]  = __builtin_amdgcn_mfma_f32_16x16x32_bf16(ahs, wO, aO[t],  0, 0, 0);
            aU[t]  = __builtin_amdgcn_mfma_f32_16x16x32_bf16(ahs, wU, aU[t],  0, 0, 0);
            aFS[t] = __builtin_amdgcn_mfma_f32_16x16x32_bf16(ahs, wF, aFS[t], 0, 0, 0);
            aF1[t] = __builtin_amdgcn_mfma_f32_16x16x32_bf16(ah1, wF, aF1[t], 0, 0, 0);
        }
    }

#pragma unroll
    for (int t = 0; t < 4; ++t) {
        int col = (nt0 + t) * 16 + (lane & 15);
        if (col < MEMC) {
            float bI = bix[col] + bih[col];
            float bO = box_[col] + boh[col];
            float bU = bux[col] + buh[col];
            float bF = bfx[col] + bfh[col];
#pragma unroll
            for (int r = 0; r < 4; ++r) {
                int row = row0 + 4 * (lane >> 4) + r;
                int b = row >> lvl;
                int off = row & (L - 1);
                int node = base + off;
                size_t o  = ((size_t)b * NNC + node) * (size_t)MEMC + col;
                size_t o1 = ((size_t)b * NNC + 2 * node + 1) * (size_t)MEMC + col;
                size_t o2 = ((size_t)b * NNC + 2 * node + 2) * (size_t)MEMC + col;
                float ig = fsig(aI[t][r] + bI);
                float og = fsig(aO[t][r] + bO);
                float ug = ftanh_(aU[t][r] + bU);
                float f1 = fsig(aFX[t][r] + aF1[t][r] + bF);
                float f2 = fsig(aFX[t][r] + (aFS[t][r] - aF1[t][r]) + bF);
                float cn = ig * ug + f1 * c[o1] + f2 * c[o2];
                c[o] = cn;
                h[o] = og * ftanh_(cn);
            }
        }
    }
}

// ---------------------------------------------------------------------------
extern "C" void kernel_launch(void* const* d_in, const int* in_sizes, int n_in,
                              void* d_out, int out_size, void* d_ws, size_t ws_size,
                              hipStream_t stream)
{
    const float* embs = (const float*)d_in[0];
    const float* Wix  = (const float*)d_in[1];
    const float* bix  = (const float*)d_in[2];
    const float* Wih  = (const float*)d_in[3];
    const float* bih  = (const float*)d_in[4];
    const float* Wfx  = (const float*)d_in[5];
    const float* bfx  = (const float*)d_in[6];
    const float* Wfh  = (const float*)d_in[7];
    const float* bfh  = (const float*)d_in[8];
    const float* Wox  = (const float*)d_in[9];
    const float* box_ = (const float*)d_in[10];
    const float* Woh  = (const float*)d_in[11];
    const float* boh  = (const float*)d_in[12];
    const float* Wux  = (const float*)d_in[13];
    const float* bux  = (const float*)d_in[14];
    const float* Wuh  = (const float*)d_in[15];
    const float* buh  = (const float*)d_in[16];

    float* h = (float*)d_out;   // (B, N, 300) fp32
    float* c = (float*)d_ws;    // (B, N, 300) fp32 scratch (78.6 MB)

    // 1) pack weights to bf16 fragments
    {
        const int total = 8 * KT_N * NT_N * 64;
        pack_w<<<(total + 255) / 256, 256, 0, stream>>>(Wix, Wih, Wfx, Wfh, Wox, Woh, Wux, Wuh);
    }

    // 2) leaf level
    {
        int rows = BBC << (DDC - 1);   // 32768
        leaf_k<<<rows / 16, 320, 0, stream>>>(embs, bix, bih, box_, boh, bux, buh, h, c);
    }

    // 3) internal levels bottom-up
    for (int lvl = DDC - 2; lvl >= 0; --lvl) {
        int rows = BBC << lvl;
        node_k<<<rows / 16, 320, 0, stream>>>(embs, bix, bih, bfx, bfh, box_, boh,
                                              bux, buh, h, c, lvl);
    }
}